// Round 11
// baseline (49.694 us; speedup 1.0000x reference)
//
#include <hip/hip_runtime.h>

typedef unsigned short u16;
typedef __bf16 bf16x8 __attribute__((ext_vector_type(8)));
typedef float f32x4 __attribute__((ext_vector_type(4)));

#define B_   16
#define H_   56
#define W_   56
#define C_   128
#define OH_  54
#define OW_  54
#define NF_  256
#define KF_  1152           // C_*9
#define M_   46656          // B_*OH_*OW_
#define NNZ_ 58982

#define XB_ELEMS (B_*H_*W_*C_)       // 6422528
#define WT_ELEMS (36*4*256*8)        // 294912 (pre-tiled [kt][ks][col][8])

__device__ __forceinline__ u16 f2bf(float f) {
    unsigned u = __float_as_uint(f);
    u += 0x7FFFu + ((u >> 16) & 1u);
    return (u16)(u >> 16);
}

__device__ __forceinline__ void gload16(const void* g, void* l) {
    __builtin_amdgcn_global_load_lds(
        (const __attribute__((address_space(1))) unsigned int*)g,
        (__attribute__((address_space(3))) unsigned int*)l,
        16, 0, 0);
}

// ---- kernel 1: x f32 -> bf16 (8/thread) + fused zeroing of wt ----
__global__ __launch_bounds__(256) void cvt_x_kernel(const float* __restrict__ x,
                                                    u16* __restrict__ xb,
                                                    u16* __restrict__ wt) {
    if (blockIdx.x < 144) {
        uint4 z = {0u, 0u, 0u, 0u};
        ((uint4*)wt)[blockIdx.x * 256 + threadIdx.x] = z;
    }
    int i = (blockIdx.x * 256 + threadIdx.x) * 8;
    float4 v0 = *(const float4*)(x + i);
    float4 v1 = *(const float4*)(x + i + 4);
    union { u16 u[8]; uint4 v; } r;
    r.u[0] = f2bf(v0.x); r.u[1] = f2bf(v0.y); r.u[2] = f2bf(v0.z); r.u[3] = f2bf(v0.w);
    r.u[4] = f2bf(v1.x); r.u[5] = f2bf(v1.y); r.u[6] = f2bf(v1.z); r.u[7] = f2bf(v1.w);
    *(uint4*)(xb + i) = r.v;
}

// ---- kernel 2: scatter sparse values into PRE-TILED W: [kt][ks][col][8] ----
__global__ __launch_bounds__(256) void scatter_kernel(const float* __restrict__ kv,
                                                      const int* __restrict__ idx,
                                                      u16* __restrict__ wt) {
    int t = blockIdx.x * 256 + threadIdx.x;
    if (t >= NNZ_) return;
    int k   = idx[2*t];      // row in [0,1152)
    int col = idx[2*t + 1];  // col in [0,256)
    int kt = k >> 5, ks = (k >> 3) & 3, e = k & 7;
    wt[(kt * 4 + ks) * 2048 + col * 8 + e] = f2bf(kv[t]);
}

// ---- kernel 3: ZERO-BARRIER wave-private pipelined implicit GEMM ----
// grid 729 (BM=64), 4 waves, wave tile 64x64. Each wave stages its OWN
// private A-tile copy (4x gload_lds = 4KB, 3-deep ring; 48KB LDS/block,
// 3 blocks/CU) -> no cross-wave deps -> NO s_barrier in the K-loop.
// B in 3-deep regsets from pre-tiled wt. Per-wave counted vmcnt(16)
// (tiles k+1,k+2 in flight = 2 phases of cover); lgkmcnt(0) WAR guard
// before LDS overwrite. T5 setprio around the MFMA cluster.
__global__ __launch_bounds__(256, 3) void spconv_gemm(const u16* __restrict__ xb,
                                                      const u16* __restrict__ wt,
                                                      const float* __restrict__ bias,
                                                      float* __restrict__ out) {
    __shared__ __align__(16) u16 As[4][3][2048];   // [wave][buf][64 rows x 32]

    const int t    = threadIdx.x;
    const int lane = t & 63;
    const int wid  = t >> 6;

    // bijective XCD swizzle (nwg=729 -> m204 formula)
    const int nwg = gridDim.x;
    const int q = nwg >> 3, r = nwg & 7;
    const int xcd = blockIdx.x & 7, inner = blockIdx.x >> 3;
    const int wg = (xcd < r ? xcd * (q + 1) : r * (q + 1) + (xcd - r) * q) + inner;
    const int m0 = wg * 64;

    // A staging (per-wave): instruction c stages rows c*16..c*16+15.
    // lane l -> row = c*16 + (l>>2), sd = l&3; src chunk = sd ^ f,
    // f = ((l>>2)&3) ^ ((l>>4)&3)  (c-invariant). 64B sectors per row.
    const int qw  = lane >> 2;
    const int kco = ((lane & 3) ^ (qw & 3) ^ ((qw >> 2) & 3)) * 8;
    const u16* a_base[4];
#pragma unroll
    for (int c = 0; c < 4; ++c) {
        int mg  = m0 + c * 16 + qw;
        int bb  = mg / (OH_ * OW_);
        int rem = mg % (OH_ * OW_);
        int ii  = rem / OW_;
        int jj  = rem % OW_;
        a_base[c] = xb + ((bb * H_ + ii) * W_ + jj) * C_;
    }
    u16* Asw = &As[wid][0][0];        // wave-uniform base

    const int ks   = lane >> 4;
    const int r16  = lane & 15;
    const int cidx = ks ^ (r16 & 3) ^ ((r16 >> 2) & 3);   // mf-invariant

    // B: per-lane byte base into pre-tiled wt; +16384B per tile.
    const char* bptr = (const char*)wt + ks * 4096 + (wid * 64 + r16) * 16;

    f32x4 acc[4][4];
    const f32x4 zz = {0.f, 0.f, 0.f, 0.f};
#pragma unroll
    for (int i = 0; i < 4; ++i)
#pragma unroll
        for (int j = 0; j < 4; ++j) acc[i][j] = zz;

    bf16x8 bs0[4], bs1[4], bs2[4];    // 3-deep B regsets

#define LOADB(dst, base, imm) \
    asm volatile("global_load_dwordx4 %0, %1, off offset:" imm \
                 : "=v"(dst) : "v"(base))

#define ISSUE_B(bset) do {                                                  \
    LOADB(bset[0], bptr, "0");   LOADB(bset[1], bptr, "256");               \
    LOADB(bset[2], bptr, "512"); LOADB(bset[3], bptr, "768");               \
    bptr += 16384;                                                          \
} while (0)

#define ISSUE_A(kn, bi) do {                                                \
    int g_  = (kn) >> 2;                                                    \
    int di_ = (g_ * 11) >> 5;                                               \
    int dj_ = g_ - 3 * di_;                                                 \
    int aoff_ = (di_ * W_ + dj_) * C_ + ((kn) & 3) * 32 + kco;              \
    gload16(a_base[0] + aoff_, Asw + (bi) * 2048);                          \
    gload16(a_base[1] + aoff_, Asw + (bi) * 2048 + 512);                    \
    gload16(a_base[2] + aoff_, Asw + (bi) * 2048 + 1024);                   \
    gload16(a_base[3] + aoff_, Asw + (bi) * 2048 + 1536);                   \
} while (0)

#define WAITVM(n)  asm volatile("s_waitcnt vmcnt(" #n ")" ::: "memory")
#define WAITLG0()  asm volatile("s_waitcnt lgkmcnt(0)" ::: "memory")
#define SB0()      __builtin_amdgcn_sched_barrier(0)

// phase: wait tile-k vmem -> ds_read frags -> lgkm0 -> overwrite-issue A(k+3)
//        -> MFMA cluster -> issue B(k+3) (after bs[bi] consumed)
#define PHASE(bi, bset, kn, ISS) do {                                       \
    WAITVM(16); SB0();                                                      \
    bf16x8 a0_ = *(const bf16x8*)(Asw + (bi) * 2048 + (r16) * 32 + cidx * 8);        \
    bf16x8 a1_ = *(const bf16x8*)(Asw + (bi) * 2048 + (16 + r16) * 32 + cidx * 8);   \
    bf16x8 a2_ = *(const bf16x8*)(Asw + (bi) * 2048 + (32 + r16) * 32 + cidx * 8);   \
    bf16x8 a3_ = *(const bf16x8*)(Asw + (bi) * 2048 + (48 + r16) * 32 + cidx * 8);   \
    WAITLG0();                                                              \
    if (ISS) ISSUE_A(kn, bi);                                               \
    __builtin_amdgcn_s_setprio(1);                                          \
    _Pragma("unroll")                                                       \
    for (int nf = 0; nf < 4; ++nf) {                                        \
        acc[0][nf] = __builtin_amdgcn_mfma_f32_16x16x32_bf16(a0_, bset[nf], acc[0][nf], 0, 0, 0); \
        acc[1][nf] = __builtin_amdgcn_mfma_f32_16x16x32_bf16(a1_, bset[nf], acc[1][nf], 0, 0, 0); \
        acc[2][nf] = __builtin_amdgcn_mfma_f32_16x16x32_bf16(a2_, bset[nf], acc[2][nf], 0, 0, 0); \
        acc[3][nf] = __builtin_amdgcn_mfma_f32_16x16x32_bf16(a3_, bset[nf], acc[3][nf], 0, 0, 0); \
    }                                                                       \
    __builtin_amdgcn_s_setprio(0);                                          \
    if (ISS) ISSUE_B(bset);                                                 \
} while (0)

    // prologue: tiles 0,1,2 in flight (8 vmem each: 4 A-gload_lds + 4 B)
    ISSUE_A(0, 0); ISSUE_B(bs0);
    ISSUE_A(1, 1); ISSUE_B(bs1);
    ISSUE_A(2, 2); ISSUE_B(bs2);

    // 33 full phases (k=0..32, issue tiles 3..35), unrolled x3 for static bufs
#pragma unroll
    for (int k2 = 0; k2 < 11; ++k2) {
        PHASE(0, bs0, 3 * k2 + 3, 1);
        PHASE(1, bs1, 3 * k2 + 4, 1);
        PHASE(2, bs2, 3 * k2 + 5, 1);
    }
    // tail: phases 33,34,35 — drain 16/8/0, no new issues
    { WAITVM(16); SB0();
      bf16x8 a0_ = *(const bf16x8*)(Asw + 0 * 2048 + (r16) * 32 + cidx * 8);
      bf16x8 a1_ = *(const bf16x8*)(Asw + 0 * 2048 + (16 + r16) * 32 + cidx * 8);
      bf16x8 a2_ = *(const bf16x8*)(Asw + 0 * 2048 + (32 + r16) * 32 + cidx * 8);
      bf16x8 a3_ = *(const bf16x8*)(Asw + 0 * 2048 + (48 + r16) * 32 + cidx * 8);
#pragma unroll
      for (int nf = 0; nf < 4; ++nf) {
        acc[0][nf] = __builtin_amdgcn_mfma_f32_16x16x32_bf16(a0_, bs0[nf], acc[0][nf], 0, 0, 0);
        acc[1][nf] = __builtin_amdgcn_mfma_f32_16x16x32_bf16(a1_, bs0[nf], acc[1][nf], 0, 0, 0);
        acc[2][nf] = __builtin_amdgcn_mfma_f32_16x16x32_bf16(a2_, bs0[nf], acc[2][nf], 0, 0, 0);
        acc[3][nf] = __builtin_amdgcn_mfma_f32_16x16x32_bf16(a3_, bs0[nf], acc[3][nf], 0, 0, 0);
      }
    }
    { WAITVM(8); SB0();
      bf16x8 a0_ = *(const bf16x8*)(Asw + 1 * 2048 + (r16) * 32 + cidx * 8);
      bf16x8 a1_ = *(const bf16x8*)(Asw + 1 * 2048 + (16 + r16) * 32 + cidx * 8);
      bf16x8 a2_ = *(const bf16x8*)(Asw + 1 * 2048 + (32 + r16) * 32 + cidx * 8);
      bf16x8 a3_ = *(const bf16x8*)(Asw + 1 * 2048 + (48 + r16) * 32 + cidx * 8);
#pragma unroll
      for (int nf = 0; nf < 4; ++nf) {
        acc[0][nf] = __builtin_amdgcn_mfma_f32_16x16x32_bf16(a0_, bs1[nf], acc[0][nf], 0, 0, 0);
        acc[1][nf] = __builtin_amdgcn_mfma_f32_16x16x32_bf16(a1_, bs1[nf], acc[1][nf], 0, 0, 0);
        acc[2][nf] = __builtin_amdgcn_mfma_f32_16x16x32_bf16(a2_, bs1[nf], acc[2][nf], 0, 0, 0);
        acc[3][nf] = __builtin_amdgcn_mfma_f32_16x16x32_bf16(a3_, bs1[nf], acc[3][nf], 0, 0, 0);
      }
    }
    { WAITVM(0); SB0();
      bf16x8 a0_ = *(const bf16x8*)(Asw + 2 * 2048 + (r16) * 32 + cidx * 8);
      bf16x8 a1_ = *(const bf16x8*)(Asw + 2 * 2048 + (16 + r16) * 32 + cidx * 8);
      bf16x8 a2_ = *(const bf16x8*)(Asw + 2 * 2048 + (32 + r16) * 32 + cidx * 8);
      bf16x8 a3_ = *(const bf16x8*)(Asw + 2 * 2048 + (48 + r16) * 32 + cidx * 8);
#pragma unroll
      for (int nf = 0; nf < 4; ++nf) {
        acc[0][nf] = __builtin_amdgcn_mfma_f32_16x16x32_bf16(a0_, bs2[nf], acc[0][nf], 0, 0, 0);
        acc[1][nf] = __builtin_amdgcn_mfma_f32_16x16x32_bf16(a1_, bs2[nf], acc[1][nf], 0, 0, 0);
        acc[2][nf] = __builtin_amdgcn_mfma_f32_16x16x32_bf16(a2_, bs2[nf], acc[2][nf], 0, 0, 0);
        acc[3][nf] = __builtin_amdgcn_mfma_f32_16x16x32_bf16(a3_, bs2[nf], acc[3][nf], 0, 0, 0);
      }
    }

#undef LOADB
#undef ISSUE_B
#undef ISSUE_A
#undef WAITVM
#undef WAITLG0
#undef SB0
#undef PHASE

    // epilogue: C/D layout col = lane&15, row = (lane>>4)*4 + reg (m89-verified)
    const int rgrp = lane >> 4;
#pragma unroll
    for (int nf = 0; nf < 4; ++nf) {
        int col  = wid * 64 + nf * 16 + r16;
        float bv = bias[col];
#pragma unroll
        for (int mf = 0; mf < 4; ++mf) {
#pragma unroll
            for (int rr = 0; rr < 4; ++rr) {
                int row = m0 + mf * 16 + rgrp * 4 + rr;
                float v = acc[mf][nf][rr] + bv;
                out[row * NF_ + col] = fmaxf(v, 0.f);
            }
        }
    }
}

extern "C" void kernel_launch(void* const* d_in, const int* in_sizes, int n_in,
                              void* d_out, int out_size, void* d_ws, size_t ws_size,
                              hipStream_t stream) {
    const float* x    = (const float*)d_in[0];
    const float* kv   = (const float*)d_in[1];
    const float* bias = (const float*)d_in[2];
    const int*   idx  = (const int*)d_in[3];
    float* out = (float*)d_out;

    u16* xb  = (u16*)d_ws;
    u16* wtp = (u16*)((char*)d_ws + (size_t)XB_ELEMS * 2);

    cvt_x_kernel<<<XB_ELEMS / (256 * 8), 256, 0, stream>>>(x, xb, wtp);
    scatter_kernel<<<(NNZ_ + 255) / 256, 256, 0, stream>>>(kv, idx, wtp);
    spconv_gemm<<<M_ / 64, 256, 0, stream>>>(xb, wtp, bias, out);
}